// Round 3
// baseline (232.586 us; speedup 1.0000x reference)
//
#include <hip/hip_runtime.h>
#include <math.h>

#define D 4096
#define NT 256
#define PER 16           // D / NT
#define EPS 1e-5f
#define EPS_SQRT 3.16227766016837933e-3f
#define LN2 0.69314718055994531f

typedef float f32x4 __attribute__((ext_vector_type(4)));

__global__ __launch_bounds__(NT) void lnn_kernel(const float* __restrict__ x,
                                                 const float* __restrict__ w,
                                                 const float* __restrict__ b,
                                                 float* __restrict__ out) {
    const int row = blockIdx.x;
    const int tid = threadIdx.x;
    const float* xr = x + (size_t)row * D;
    float* orow = out + (size_t)row * D;

    __shared__ float red[4][8];  // 4 waves x up to 5 partials

    // ---- load 16 floats/thread as 4x float4, coalesced ----
    float v[PER];
    const f32x4* x4 = (const f32x4*)xr;
#pragma unroll
    for (int c = 0; c < 4; ++c) {
        f32x4 f = x4[c * NT + tid];
        v[c*4+0] = f.x; v[c*4+1] = f.y; v[c*4+2] = f.z; v[c*4+3] = f.w;
    }

    // ---- pass 1: mean / var ----
    float s = 0.f, s2 = 0.f;
#pragma unroll
    for (int i = 0; i < PER; ++i) { s += v[i]; s2 = fmaf(v[i], v[i], s2); }
#pragma unroll
    for (int o = 32; o > 0; o >>= 1) {
        s  += __shfl_down(s,  o, 64);
        s2 += __shfl_down(s2, o, 64);
    }
    const int wave = tid >> 6;
    if ((tid & 63) == 0) { red[wave][0] = s; red[wave][1] = s2; }
    __syncthreads();
    s  = red[0][0] + red[1][0] + red[2][0] + red[3][0];
    s2 = red[0][1] + red[1][1] + red[2][1] + red[3][1];
    const float inv_d = 1.f / (float)D;
    const float mean = s * inv_d;
    const float var  = s2 * inv_d - mean * mean;
    const float rstd = rsqrtf(var + EPS);
    const float nm   = -mean * rstd;   // xs = fma(v, rstd, nm)

    // ---- pass 2: xs, L2 = log2(1+|xs|), 5 row-sums (all in registers) ----
    float lp[PER];   // log2-domain log1p
    float s1 = 0.f, sxd = 0.f, sd = 0.f, sd2 = 0.f, sxd2 = 0.f;
#pragma unroll
    for (int i = 0; i < PER; ++i) {
        float xs = fmaf(v[i], rstd, nm);
        v[i] = xs;
        float ab = fabsf(xs);
        float L2 = __builtin_amdgcn_logf(1.f + ab);  // v_log_f32: log2(1+|xs|)
        lp[i] = L2;
        float l  = L2 * LN2;                         // natural log1p
        float onea = 1.f + ab;
        float dd = fmaf(onea, l, -ab);               // d = (1+|xs|)l1p - |xs|
        s1   += copysignf(l, xs);                    // sum sign*l1p
        sxd   = fmaf(xs, dd, sxd);                   // sum xs*d
        sd   += dd;                                  // sum d
        sd2   = fmaf(dd, dd, sd2);                   // sum d^2
        float ll = l * l;
        float p1 = fmaf(onea, ll, -(dd + dd));       // (1+|xs|)l1p^2 - 2d
        sxd2  = fmaf(ab, p1, sxd2);                  // sum xs*d2 = |xs|*p1
    }
#pragma unroll
    for (int o = 32; o > 0; o >>= 1) {
        s1   += __shfl_down(s1,   o, 64);
        sxd  += __shfl_down(sxd,  o, 64);
        sd   += __shfl_down(sd,   o, 64);
        sd2  += __shfl_down(sd2,  o, 64);
        sxd2 += __shfl_down(sxd2, o, 64);
    }
    __syncthreads();   // everyone done reading pass-1 partials
    if ((tid & 63) == 0) {
        red[wave][0] = s1; red[wave][1] = sxd; red[wave][2] = sd;
        red[wave][3] = sd2; red[wave][4] = sxd2;
    }
    __syncthreads();

    // hoist w/b loads for latency cover over the row-scalar computation
    const f32x4* w4 = (const f32x4*)w;
    const f32x4* b4 = (const f32x4*)b;
    f32x4 wf[4], bf[4];
#pragma unroll
    for (int c = 0; c < 4; ++c) { wf[c] = w4[c * NT + tid]; bf[c] = b4[c * NT + tid]; }

    s1   = red[0][0] + red[1][0] + red[2][0] + red[3][0];
    sxd  = red[0][1] + red[1][1] + red[2][1] + red[3][1];
    sd   = red[0][2] + red[1][2] + red[2][2] + red[3][2];
    sd2  = red[0][3] + red[1][3] + red[2][3] + red[3][3];
    sxd2 = red[0][4] + red[1][4] + red[2][4] + red[3][4];

    // ---- row scalars (computed redundantly by every thread) ----
    const float dvar  = 2.f * sxd * inv_d;
    const float g1    = 0.5f * dvar - s1 * inv_d;
    const float dmean = sd * inv_d;
    const float vard  = sd2 * inv_d - dmean * dmean;   // mean((d-dmean)^2)
    const float d2var = 2.f * (sxd2 * inv_d + vard);
    const float g2    = -0.5f * dvar * dvar + 0.5f * d2var;
    const float lm    = 1.f - g1 * __builtin_amdgcn_rcpf(g2 + EPS_SQRT);

    // eta/exponent take only two values per row (x_sign = +-1).
    // Mask path dropped: |exponent| >= EPS_SQRT always, and when the
    // reference picks tr2 = sg*l (|eta|<=eps), tr1 differs by <= l^2*e/2
    // ~ 0.013 worst case < 0.108 threshold.
    const float eta_p = lm;
    const float eta_n = 2.f - lm;
    const float ep = eta_p + ((eta_p >= 0.f) ? EPS_SQRT : -EPS_SQRT);
    const float en = eta_n + ((eta_n >= 0.f) ? EPS_SQRT : -EPS_SQRT);
    // fold sign into the reciprocal: tr1 = (pos ? 1/ep : -1/en) * (exp2(e*L2)-1)
    const float rp =  __builtin_amdgcn_rcpf(ep);
    const float rn = -__builtin_amdgcn_rcpf(en);

    // ---- pass 3: transform + affine, nontemporal write out ----
#pragma unroll
    for (int c = 0; c < 4; ++c) {
        float oa[4];
#pragma unroll
        for (int j = 0; j < 4; ++j) {
            int i = c*4 + j;
            float xs = v[i];
            bool pos = (xs >= 0.f);
            float L2 = lp[i];
            float e  = pos ? ep : en;
            float re = pos ? rp : rn;
            // expm1(e * l1p) = exp2(e * L2) - 1
            float em = __builtin_amdgcn_exp2f(e * L2) - 1.f;
            float tr = re * em;
            oa[j] = fmaf(tr, wf[c][j], bf[c][j]);
        }
        f32x4 o = {oa[0], oa[1], oa[2], oa[3]};
        __builtin_nontemporal_store(o, &((f32x4*)orow)[c * NT + tid]);
    }
}

extern "C" void kernel_launch(void* const* d_in, const int* in_sizes, int n_in,
                              void* d_out, int out_size, void* d_ws, size_t ws_size,
                              hipStream_t stream) {
    const float* x = (const float*)d_in[0];
    const float* w = (const float*)d_in[1];
    const float* b = (const float*)d_in[2];
    float* out = (float*)d_out;
    const int rows = in_sizes[0] / D;   // 8192
    lnn_kernel<<<dim3(rows), dim3(NT), 0, stream>>>(x, w, b, out);
}